// Round 9
// baseline (228.548 us; speedup 1.0000x reference)
//
#include <hip/hip_runtime.h>
#include <hip/hip_bf16.h>

// Capsule dynamic routing, round 9: cvt_x folded into pass-0, C transposed.
// x[64][2048][16] f32, W[32][2048][16][16] f32 -> v[64][32][16] f32.
//
// Pipeline (8 dispatches; carry only vsumT[n][b][d]):
//   pass0: wsum0_cvt (reads W f32 + x f32 ONCE; writes Wt[j][n][256] bf16 and
//          xt[j][b][16] bf16 as side effects; accumulates uniform-c partials)
//          -> reduce(first)
//   pass1,2: LS (fused logits+softmax -> C[j][b][n] bf16), wsum, reduce
//
// Round-9 deltas vs 8: cvt_x dispatch deleted (x converted in wsum0 by the
// y==0/w==0 wave); C relaid [j][b][n] so LS stores are 64B-contiguous per lane
// (was 32 scattered 2B stores at 128B stride); wsum reads C as broadcast
// dword gathers (L1-hot).
//
// MFMA layouts (m89/m91/m120-verified): C/D col=lane&15, row=(lane>>4)*4+reg;
// A[m=lane&15][k=(lane>>4)*8+t]. K=32 packs 2 j per MFMA (k<16 -> j0, k>=16 -> j1).

#define J_DIM 2048
#define NCH 128            // wsum j-chunks (16 j each)

typedef __attribute__((ext_vector_type(8))) short bf16x8;
typedef __attribute__((ext_vector_type(4))) short bf16x4;
typedef __attribute__((ext_vector_type(4))) float f32x4;

__device__ inline short f2bf(float f) {
    union { float f; unsigned u; } v; v.f = f;
    unsigned r = v.u + 0x7FFFu + ((v.u >> 16) & 1u);   // RNE
    return (short)(r >> 16);
}
__device__ inline float bf2f(short s) {
    union { unsigned u; float f; } v; v.u = ((unsigned)(unsigned short)s) << 16;
    return v.f;
}

// Pass 0: read W f32 + x f32 once; write Wt (all waves) and xt (y==0,w==0 wave);
// accumulate uniform-c (1/32) partials. grid(NCH, 8) x 256 thr.
__global__ __launch_bounds__(256)
void wsum0_cvt_k(const float* __restrict__ W, const float* __restrict__ x,
                 short* __restrict__ Wt, short* __restrict__ xt,
                 short* __restrict__ sp) {
    const int t = threadIdx.x, lane = t & 63, w = t >> 6;
    const int col = lane & 15, g = lane >> 4;
    const int n = blockIdx.y * 4 + w;
    const int chunk = blockIdx.x;
    const bool write_xt = (blockIdx.y == 0) && (w == 0);

    f32x4 acc[4];
#pragma unroll
    for (int bt = 0; bt < 4; ++bt) acc[bt] = (f32x4){0.f, 0.f, 0.f, 0.f};

#pragma unroll
    for (int jp = 0; jp < 8; ++jp) {
        const int jq = chunk * 16 + jp * 2 + (g >> 1);
        // lane's 8 f32 of W[n][jq]; wave covers two adjacent 1KB rows contiguously
        const float4* wsrc = (const float4*)(W + ((size_t)n * J_DIM + jq) * 256 + col * 16 + (g & 1) * 8);
        float4 a = wsrc[0], b2 = wsrc[1];
        short tmp[8] = { f2bf(a.x), f2bf(a.y), f2bf(a.z), f2bf(a.w),
                         f2bf(b2.x), f2bf(b2.y), f2bf(b2.z), f2bf(b2.w) };
        bf16x8 af = *(bf16x8*)tmp;
        *(bf16x8*)(Wt + ((size_t)jq * 32 + n) * 256 + col * 16 + (g & 1) * 8) = af;
#pragma unroll
        for (int bt = 0; bt < 4; ++bt) {
            const int b = bt * 16 + col;
            const float4* xp = (const float4*)(x + ((size_t)b * J_DIM + jq) * 16 + (g & 1) * 8);
            float4 x0 = xp[0], x1 = xp[1];
            float xf[8] = { x0.x, x0.y, x0.z, x0.w, x1.x, x1.y, x1.z, x1.w };
            if (write_xt) {
                short xs[8] = { f2bf(xf[0]), f2bf(xf[1]), f2bf(xf[2]), f2bf(xf[3]),
                                f2bf(xf[4]), f2bf(xf[5]), f2bf(xf[6]), f2bf(xf[7]) };
                *(bf16x8*)(xt + ((size_t)jq * 64 + b) * 16 + (g & 1) * 8) = *(bf16x8*)xs;
            }
            short bs[8];
#pragma unroll
            for (int k = 0; k < 8; ++k) bs[k] = f2bf(0.03125f * xf[k]);
            acc[bt] = __builtin_amdgcn_mfma_f32_16x16x32_bf16(af, *(bf16x8*)bs, acc[bt], 0, 0, 0);
        }
    }
#pragma unroll
    for (int bt = 0; bt < 4; ++bt) {
        short o[4] = { f2bf(acc[bt][0]), f2bf(acc[bt][1]), f2bf(acc[bt][2]), f2bf(acc[bt][3]) };
        *(bf16x4*)(sp + (((size_t)chunk * 32 + n) * 64 + bt * 16 + col) * 16 + g * 4) = *(bf16x4*)o;
    }
}

// C[j][b][n] bf16 = softmax_n( vsumT[n,b,:] . u_hat[b,n,j,:] )
// grid(2048) x 256 thr; wave = b-tile, block = one j (16KB contiguous Wt slab).
__global__ __launch_bounds__(256)
void logits_softmax_k(const short* __restrict__ Wt, const short* __restrict__ xt,
                      const float* __restrict__ vsumT, short* __restrict__ C) {
    const int t = threadIdx.x, lane = t & 63, bt = t >> 6;
    const int col = lane & 15, g = lane >> 4;
    const int j = blockIdx.x;
    const int b = bt * 16 + col;

    bf16x8 xb = (bf16x8){0, 0, 0, 0, 0, 0, 0, 0};
    if (lane < 32)
        xb = *(const bf16x8*)(xt + ((size_t)j * 64 + b) * 16 + (g & 1) * 8);

    float logit[32];
#pragma unroll
    for (int n = 0; n < 32; ++n) {
        // A[m=col=d][k=g*8+t]; k>=16 lanes read garbage (nulled by xb=0)
        bf16x8 af = *(const bf16x8*)(Wt + ((size_t)j * 32 + n) * 256 + col * 16 + g * 8);
        f32x4 u = __builtin_amdgcn_mfma_f32_16x16x32_bf16(
            af, xb, (f32x4){0.f, 0.f, 0.f, 0.f}, 0, 0, 0);
        float4 vv = *(const float4*)(vsumT + ((size_t)n * 64 + b) * 16 + g * 4);
        float lp = vv.x * u[0] + vv.y * u[1] + vv.z * u[2] + vv.w * u[3];
        lp += __shfl_xor(lp, 16);
        lp += __shfl_xor(lp, 32);          // all lanes: logit(b, n)
        logit[n] = lp;
    }

    float mx = logit[0];
#pragma unroll
    for (int n = 1; n < 32; ++n) mx = fmaxf(mx, logit[n]);
    float Z = 0.f;
#pragma unroll
    for (int n = 0; n < 32; ++n) { logit[n] = __expf(logit[n] - mx); Z += logit[n]; }
    float rz = __builtin_amdgcn_rcpf(Z);

    if (g == 0) {
        // contiguous 64B per lane; wave stores 1KB
        short cs[32];
#pragma unroll
        for (int n = 0; n < 32; ++n) cs[n] = f2bf(logit[n] * rz);
        short* row = C + ((size_t)j * 64 + b) * 32;
        *(bf16x8*)(row)      = *(bf16x8*)&cs[0];
        *(bf16x8*)(row + 8)  = *(bf16x8*)&cs[8];
        *(bf16x8*)(row + 16) = *(bf16x8*)&cs[16];
        *(bf16x8*)(row + 24) = *(bf16x8*)&cs[24];
    }
}

// sp[chunk][n][b][d] bf16 = sum_{j in 16-chunk} c[b,n,j] * u_hat[b,n,j,d]
// grid(NCH, 8) x 256 thr; wave = (chunk, n); 4 b-tiles in-wave; 4 waves/SIMD.
__global__ __launch_bounds__(256)
void wsum_k(const short* __restrict__ Wt, const short* __restrict__ xt,
            const short* __restrict__ C, short* __restrict__ sp) {
    const int t = threadIdx.x, lane = t & 63, w = t >> 6;
    const int col = lane & 15, g = lane >> 4;
    const int n = blockIdx.y * 4 + w;
    const int chunk = blockIdx.x;

    f32x4 acc[4];
#pragma unroll
    for (int bt = 0; bt < 4; ++bt) acc[bt] = (f32x4){0.f, 0.f, 0.f, 0.f};

#pragma unroll
    for (int jp = 0; jp < 8; ++jp) {
        const int jq = chunk * 16 + jp * 2 + (g >> 1);
        bf16x8 af = *(const bf16x8*)(Wt + ((size_t)jq * 32 + n) * 256 + col * 16 + (g & 1) * 8);
#pragma unroll
        for (int bt = 0; bt < 4; ++bt) {
            const int b = bt * 16 + col;
            bf16x8 xr = *(const bf16x8*)(xt + ((size_t)jq * 64 + b) * 16 + (g & 1) * 8);
            float cc = bf2f(C[((size_t)jq * 64 + b) * 32 + n]);   // L1-hot broadcast
            short bs[8];
#pragma unroll
            for (int k = 0; k < 8; ++k) bs[k] = f2bf(cc * bf2f(xr[k]));
            acc[bt] = __builtin_amdgcn_mfma_f32_16x16x32_bf16(af, *(bf16x8*)bs, acc[bt], 0, 0, 0);
        }
    }
#pragma unroll
    for (int bt = 0; bt < 4; ++bt) {
        short o[4] = { f2bf(acc[bt][0]), f2bf(acc[bt][1]), f2bf(acc[bt][2]), f2bf(acc[bt][3]) };
        *(bf16x4*)(sp + (((size_t)chunk * 32 + n) * 64 + bt * 16 + col) * 16 + g * 4) = *(bf16x4*)o;
    }
}

// fold NCH bf16 chunk partials, squash, update vsumT / write out. wave per (n,b).
__global__ __launch_bounds__(256)
void reduce_k(const short* __restrict__ sp, float* __restrict__ vsumT,
              float* __restrict__ out, int is_first, int is_last) {
    const int t = threadIdx.x, lane = t & 63, w = t >> 6;
    const int q = blockIdx.x * 4 + w;       // 0..2047
    const int n = q >> 6, b = q & 63;
    const int d4 = lane & 3, ch = lane >> 2;   // ch 0..15

    float4 a = make_float4(0.f, 0.f, 0.f, 0.f);
#pragma unroll
    for (int m = 0; m < NCH / 16; ++m) {
        bf16x4 v = *(const bf16x4*)(sp + (((size_t)(ch + 16 * m) * 32 + n) * 64 + b) * 16 + d4 * 4);
        a.x += bf2f(v[0]); a.y += bf2f(v[1]); a.z += bf2f(v[2]); a.w += bf2f(v[3]);
    }
#pragma unroll
    for (int mk = 4; mk <= 32; mk <<= 1) {
        a.x += __shfl_xor(a.x, mk); a.y += __shfl_xor(a.y, mk);
        a.z += __shfl_xor(a.z, mk); a.w += __shfl_xor(a.w, mk);
    }
    float tt = a.x * a.x + a.y * a.y + a.z * a.z + a.w * a.w;
    tt += __shfl_xor(tt, 1);
    tt += __shfl_xor(tt, 2);
    float s2 = tt + 1e-7f;
    float scale = sqrtf(s2) / (1.0f + s2);

    if (lane < 4) {
        float4 v = make_float4(a.x * scale, a.y * scale, a.z * scale, a.w * scale);
        if (is_last) {
            *(float4*)(out + ((size_t)b * 32 + n) * 16 + d4 * 4) = v;   // [b][n][d]
        } else {
            float* p = vsumT + ((size_t)n * 64 + b) * 16 + d4 * 4;      // [n][b][d]
            if (is_first) {
                *(float4*)p = v;
            } else {
                float4 o = *(const float4*)p;
                *(float4*)p = make_float4(o.x + v.x, o.y + v.y, o.z + v.z, o.w + v.w);
            }
        }
    }
}

extern "C" void kernel_launch(void* const* d_in, const int* in_sizes, int n_in,
                              void* d_out, int out_size, void* d_ws, size_t ws_size,
                              hipStream_t stream) {
    const float* x = (const float*)d_in[0];   // [64,2048,16]
    const float* W = (const float*)d_in[1];   // [32,2048,16,16]
    float* out = (float*)d_out;               // [64,32,16]

    char* wsb = (char*)d_ws;
    short* Wt    = (short*)(wsb);                        // 32 MB + 2KB slack
    short* xt    = (short*)(wsb + 33556480);             // 4.2 MB [j][b][16]
    short* C     = (short*)(wsb + 37750784);             // 8.4 MB [j][b][n] bf16
    short* sp    = (short*)(wsb + 46139392);             // 8.4 MB [chunk][n][b][d] bf16
    float* vsumT = (float*)(wsb + 54528000);             // 128 KB [n][b][d]

    // pass 0: logits == 0 -> uniform c; W and x converted/transposed in-flight
    wsum0_cvt_k<<<dim3(NCH, 8), 256, 0, stream>>>(W, x, Wt, xt, sp);
    reduce_k<<<512, 256, 0, stream>>>(sp, vsumT, out, 1, 0);
    // pass 1
    logits_softmax_k<<<2048, 256, 0, stream>>>(Wt, xt, vsumT, C);
    wsum_k<<<dim3(NCH, 8), 256, 0, stream>>>(Wt, xt, C, sp);
    reduce_k<<<512, 256, 0, stream>>>(sp, vsumT, out, 0, 0);
    // pass 2
    logits_softmax_k<<<2048, 256, 0, stream>>>(Wt, xt, vsumT, C);
    wsum_k<<<dim3(NCH, 8), 256, 0, stream>>>(Wt, xt, C, sp);
    reduce_k<<<512, 256, 0, stream>>>(sp, vsumT, out, 0, 1);
}

// Round 10
// 200.176 us; speedup vs baseline: 1.1417x; 1.1417x over previous
//
#include <hip/hip_runtime.h>
#include <hip/hip_bf16.h>

// Capsule dynamic routing, round 10 == round 8 (measured optimum, 200.9 us).
// Round 9's two layout trades (x f32 gather folded into wsum0; C transpose)
// both regressed coalescing and are reverted.
// x[64][2048][16] f32, W[32][2048][16][16] f32 -> v[64][32][16] f32.
//
// Pipeline (carry only vsumT[n][b][d]):
//   cvt_x (j-fast, coalesced both sides)
//   pass0: wsum0_cvt (reads f32 W ONCE coalesced, converts+writes Wt[j][n][256]
//          bf16, accumulates uniform-c partials) -> reduce(first=1)
//   pass1,2: LS (fused logits+softmax -> C[j][n][b] bf16), wsum, reduce
//   9 dispatches total.
//
// MFMA layouts (m89/m91/m120-verified): C/D col=lane&15, row=(lane>>4)*4+reg;
// A[m=lane&15][k=(lane>>4)*8+t]. K=32 packs 2 j per MFMA (k<16 -> j0, k>=16 -> j1).

#define J_DIM 2048
#define NCH 128            // wsum j-chunks (16 j each)

typedef __attribute__((ext_vector_type(8))) short bf16x8;
typedef __attribute__((ext_vector_type(4))) short bf16x4;
typedef __attribute__((ext_vector_type(4))) float f32x4;

__device__ inline short f2bf(float f) {
    union { float f; unsigned u; } v; v.f = f;
    unsigned r = v.u + 0x7FFFu + ((v.u >> 16) & 1u);   // RNE
    return (short)(r >> 16);
}
__device__ inline float bf2f(short s) {
    union { unsigned u; float f; } v; v.u = ((unsigned)(unsigned short)s) << 16;
    return v.f;
}

// x[b][j][16] f32 -> xt[j][b][16] bf16. One thread per (b,j) row.
__global__ __launch_bounds__(256)
void cvt_x_t(const float* __restrict__ x, short* __restrict__ xt) {
    const int id = blockIdx.x * 256 + threadIdx.x;   // j fast for coalesced reads
    const int j = id & (J_DIM - 1), b = id >> 11;
    const float4* s = (const float4*)(x + ((size_t)b * J_DIM + j) * 16);
    float4 q0 = s[0], q1 = s[1], q2 = s[2], q3 = s[3];
    short tmp[16] = { f2bf(q0.x), f2bf(q0.y), f2bf(q0.z), f2bf(q0.w),
                      f2bf(q1.x), f2bf(q1.y), f2bf(q1.z), f2bf(q1.w),
                      f2bf(q2.x), f2bf(q2.y), f2bf(q2.z), f2bf(q2.w),
                      f2bf(q3.x), f2bf(q3.y), f2bf(q3.z), f2bf(q3.w) };
    short* d = xt + ((size_t)j * 64 + b) * 16;
    *(bf16x8*)d = *(bf16x8*)tmp;
    *(bf16x8*)(d + 8) = *(bf16x8*)&tmp[8];
}

// Pass 0: read W f32 once (coalesced 1KB-row bursts), convert, write
// Wt[j][n][256] bf16, accumulate uniform-c (1/32) partials.
// grid(NCH, 8) x 256 thr; wave = (16-j chunk, n); 4 b-tiles in-wave.
__global__ __launch_bounds__(256)
void wsum0_cvt_k(const float* __restrict__ W, short* __restrict__ Wt,
                 const short* __restrict__ xt, short* __restrict__ sp) {
    const int t = threadIdx.x, lane = t & 63, w = t >> 6;
    const int col = lane & 15, g = lane >> 4;
    const int n = blockIdx.y * 4 + w;
    const int chunk = blockIdx.x;

    f32x4 acc[4];
#pragma unroll
    for (int bt = 0; bt < 4; ++bt) acc[bt] = (f32x4){0.f, 0.f, 0.f, 0.f};

#pragma unroll
    for (int jp = 0; jp < 8; ++jp) {
        const int jq = chunk * 16 + jp * 2 + (g >> 1);
        // lane's 8 f32 of W[n][jq] row; half-wave covers the full 1KB row
        const float4* wsrc = (const float4*)(W + ((size_t)n * J_DIM + jq) * 256 + col * 16 + (g & 1) * 8);
        float4 a = wsrc[0], b2 = wsrc[1];
        short tmp[8] = { f2bf(a.x), f2bf(a.y), f2bf(a.z), f2bf(a.w),
                         f2bf(b2.x), f2bf(b2.y), f2bf(b2.z), f2bf(b2.w) };
        bf16x8 af = *(bf16x8*)tmp;
        *(bf16x8*)(Wt + ((size_t)jq * 32 + n) * 256 + col * 16 + (g & 1) * 8) = af;
#pragma unroll
        for (int bt = 0; bt < 4; ++bt) {
            const int b = bt * 16 + col;
            bf16x8 xr = *(const bf16x8*)(xt + ((size_t)jq * 64 + b) * 16 + (g & 1) * 8);
            short bs[8];
#pragma unroll
            for (int k = 0; k < 8; ++k) bs[k] = f2bf(0.03125f * bf2f(xr[k]));
            acc[bt] = __builtin_amdgcn_mfma_f32_16x16x32_bf16(af, *(bf16x8*)bs, acc[bt], 0, 0, 0);
        }
    }
#pragma unroll
    for (int bt = 0; bt < 4; ++bt) {
        short o[4] = { f2bf(acc[bt][0]), f2bf(acc[bt][1]), f2bf(acc[bt][2]), f2bf(acc[bt][3]) };
        *(bf16x4*)(sp + (((size_t)chunk * 32 + n) * 64 + bt * 16 + col) * 16 + g * 4) = *(bf16x4*)o;
    }
}

// C[j][n][b] bf16 = softmax_n( vsumT[n,b,:] . u_hat[b,n,j,:] )
// grid(2048) x 256 thr; wave = b-tile, block = one j (16KB contiguous Wt slab).
__global__ __launch_bounds__(256)
void logits_softmax_k(const short* __restrict__ Wt, const short* __restrict__ xt,
                      const float* __restrict__ vsumT, short* __restrict__ C) {
    const int t = threadIdx.x, lane = t & 63, bt = t >> 6;
    const int col = lane & 15, g = lane >> 4;
    const int j = blockIdx.x;
    const int b = bt * 16 + col;

    bf16x8 xb = (bf16x8){0, 0, 0, 0, 0, 0, 0, 0};
    if (lane < 32)
        xb = *(const bf16x8*)(xt + ((size_t)j * 64 + b) * 16 + (g & 1) * 8);

    float logit[32];
#pragma unroll
    for (int n = 0; n < 32; ++n) {
        // A[m=col=d][k=g*8+t]; k>=16 lanes read garbage (nulled by xb=0)
        bf16x8 af = *(const bf16x8*)(Wt + ((size_t)j * 32 + n) * 256 + col * 16 + g * 8);
        f32x4 u = __builtin_amdgcn_mfma_f32_16x16x32_bf16(
            af, xb, (f32x4){0.f, 0.f, 0.f, 0.f}, 0, 0, 0);
        float4 vv = *(const float4*)(vsumT + ((size_t)n * 64 + b) * 16 + g * 4);
        float lp = vv.x * u[0] + vv.y * u[1] + vv.z * u[2] + vv.w * u[3];
        lp += __shfl_xor(lp, 16);
        lp += __shfl_xor(lp, 32);          // all lanes: logit(b, n)
        logit[n] = lp;
    }

    float mx = logit[0];
#pragma unroll
    for (int n = 1; n < 32; ++n) mx = fmaxf(mx, logit[n]);
    float Z = 0.f;
#pragma unroll
    for (int n = 0; n < 32; ++n) { logit[n] = __expf(logit[n] - mx); Z += logit[n]; }
    float rz = __builtin_amdgcn_rcpf(Z);

    if (g == 0) {
        short* row = C + (size_t)j * 32 * 64 + b;
#pragma unroll
        for (int n = 0; n < 32; ++n) row[n * 64] = f2bf(logit[n] * rz);
    }
}

// sp[chunk][n][b][d] bf16 = sum_{j in 16-chunk} c[b,n,j] * u_hat[b,n,j,d]
// grid(NCH, 8) x 256 thr; wave = (chunk, n); 4 b-tiles in-wave; 4 waves/SIMD.
__global__ __launch_bounds__(256)
void wsum_k(const short* __restrict__ Wt, const short* __restrict__ xt,
            const short* __restrict__ C, short* __restrict__ sp) {
    const int t = threadIdx.x, lane = t & 63, w = t >> 6;
    const int col = lane & 15, g = lane >> 4;
    const int n = blockIdx.y * 4 + w;
    const int chunk = blockIdx.x;

    f32x4 acc[4];
#pragma unroll
    for (int bt = 0; bt < 4; ++bt) acc[bt] = (f32x4){0.f, 0.f, 0.f, 0.f};

#pragma unroll
    for (int jp = 0; jp < 8; ++jp) {
        const int jq = chunk * 16 + jp * 2 + (g >> 1);
        bf16x8 af = *(const bf16x8*)(Wt + ((size_t)jq * 32 + n) * 256 + col * 16 + (g & 1) * 8);
#pragma unroll
        for (int bt = 0; bt < 4; ++bt) {
            const int b = bt * 16 + col;
            bf16x8 xr = *(const bf16x8*)(xt + ((size_t)jq * 64 + b) * 16 + (g & 1) * 8);
            float cc = bf2f(C[((size_t)jq * 32 + n) * 64 + b]);   // 32B contiguous/wave
            short bs[8];
#pragma unroll
            for (int k = 0; k < 8; ++k) bs[k] = f2bf(cc * bf2f(xr[k]));
            acc[bt] = __builtin_amdgcn_mfma_f32_16x16x32_bf16(af, *(bf16x8*)bs, acc[bt], 0, 0, 0);
        }
    }
#pragma unroll
    for (int bt = 0; bt < 4; ++bt) {
        short o[4] = { f2bf(acc[bt][0]), f2bf(acc[bt][1]), f2bf(acc[bt][2]), f2bf(acc[bt][3]) };
        *(bf16x4*)(sp + (((size_t)chunk * 32 + n) * 64 + bt * 16 + col) * 16 + g * 4) = *(bf16x4*)o;
    }
}

// fold NCH bf16 chunk partials, squash, update vsumT / write out. wave per (n,b).
// is_first: STORE vsum (replaces a memset dispatch).
__global__ __launch_bounds__(256)
void reduce_k(const short* __restrict__ sp, float* __restrict__ vsumT,
              float* __restrict__ out, int is_first, int is_last) {
    const int t = threadIdx.x, lane = t & 63, w = t >> 6;
    const int q = blockIdx.x * 4 + w;       // 0..2047
    const int n = q >> 6, b = q & 63;
    const int d4 = lane & 3, ch = lane >> 2;   // ch 0..15

    float4 a = make_float4(0.f, 0.f, 0.f, 0.f);
#pragma unroll
    for (int m = 0; m < NCH / 16; ++m) {
        bf16x4 v = *(const bf16x4*)(sp + (((size_t)(ch + 16 * m) * 32 + n) * 64 + b) * 16 + d4 * 4);
        a.x += bf2f(v[0]); a.y += bf2f(v[1]); a.z += bf2f(v[2]); a.w += bf2f(v[3]);
    }
#pragma unroll
    for (int mk = 4; mk <= 32; mk <<= 1) {
        a.x += __shfl_xor(a.x, mk); a.y += __shfl_xor(a.y, mk);
        a.z += __shfl_xor(a.z, mk); a.w += __shfl_xor(a.w, mk);
    }
    float tt = a.x * a.x + a.y * a.y + a.z * a.z + a.w * a.w;
    tt += __shfl_xor(tt, 1);
    tt += __shfl_xor(tt, 2);
    float s2 = tt + 1e-7f;
    float scale = sqrtf(s2) / (1.0f + s2);

    if (lane < 4) {
        float4 v = make_float4(a.x * scale, a.y * scale, a.z * scale, a.w * scale);
        if (is_last) {
            *(float4*)(out + ((size_t)b * 32 + n) * 16 + d4 * 4) = v;   // [b][n][d]
        } else {
            float* p = vsumT + ((size_t)n * 64 + b) * 16 + d4 * 4;      // [n][b][d]
            if (is_first) {
                *(float4*)p = v;
            } else {
                float4 o = *(const float4*)p;
                *(float4*)p = make_float4(o.x + v.x, o.y + v.y, o.z + v.z, o.w + v.w);
            }
        }
    }
}

extern "C" void kernel_launch(void* const* d_in, const int* in_sizes, int n_in,
                              void* d_out, int out_size, void* d_ws, size_t ws_size,
                              hipStream_t stream) {
    const float* x = (const float*)d_in[0];   // [64,2048,16]
    const float* W = (const float*)d_in[1];   // [32,2048,16,16]
    float* out = (float*)d_out;               // [64,32,16]

    char* wsb = (char*)d_ws;
    short* Wt    = (short*)(wsb);                        // 32 MB + slack
    short* xt    = (short*)(wsb + 33556480);             // 4.2 MB [j][b][16]
    short* C     = (short*)(wsb + 37750784);             // 8.4 MB [j][n][b] bf16
    short* sp    = (short*)(wsb + 46139392);             // 8.4 MB [chunk][n][b][d] bf16
    float* vsumT = (float*)(wsb + 54528000);             // 128 KB [n][b][d]

    cvt_x_t<<<512, 256, 0, stream>>>(x, xt);

    // pass 0: logits == 0 -> uniform c; W converted+transposed in-flight
    wsum0_cvt_k<<<dim3(NCH, 8), 256, 0, stream>>>(W, Wt, xt, sp);
    reduce_k<<<512, 256, 0, stream>>>(sp, vsumT, out, 1, 0);
    // pass 1
    logits_softmax_k<<<2048, 256, 0, stream>>>(Wt, xt, vsumT, C);
    wsum_k<<<dim3(NCH, 8), 256, 0, stream>>>(Wt, xt, C, sp);
    reduce_k<<<512, 256, 0, stream>>>(sp, vsumT, out, 0, 0);
    // pass 2
    logits_softmax_k<<<2048, 256, 0, stream>>>(Wt, xt, vsumT, C);
    wsum_k<<<dim3(NCH, 8), 256, 0, stream>>>(Wt, xt, C, sp);
    reduce_k<<<512, 256, 0, stream>>>(sp, vsumT, out, 0, 1);
}